// Round 2
// baseline (564.968 us; speedup 1.0000x reference)
//
#include <hip/hip_runtime.h>
#include <hip/hip_bf16.h>
#include <stdint.h>

// Problem dims (fixed for this problem instance)
#define MD 8192
#define ND 4096
#define KD 4096
#define RD 32

typedef __bf16 bf16x8 __attribute__((ext_vector_type(8)));
typedef float f32x4 __attribute__((ext_vector_type(4)));

// async 16B global->LDS (wave-uniform LDS base + lane*16 scatter)
__device__ __forceinline__ void cp16(const void* g, void* l) {
    __builtin_amdgcn_global_load_lds(
        (const __attribute__((address_space(1))) void*)g,
        (__attribute__((address_space(3))) void*)l, 16, 0, 0);
}

// ---------------------------------------------------------------------------
// Kernel 1: x fp32 -> bf16  (8 elems/thread, 16B stores)
// ---------------------------------------------------------------------------
__global__ __launch_bounds__(256) void cvt_x(const float* __restrict__ x,
                                             __hip_bfloat16* __restrict__ y) {
    size_t i = ((size_t)blockIdx.x * 256 + threadIdx.x) * 8;
    float4 a = *(const float4*)(x + i);
    float4 b = *(const float4*)(x + i + 4);
    union { __hip_bfloat16 h[8]; uint4 u; } o;
    o.h[0] = __float2bfloat16(a.x); o.h[1] = __float2bfloat16(a.y);
    o.h[2] = __float2bfloat16(a.z); o.h[3] = __float2bfloat16(a.w);
    o.h[4] = __float2bfloat16(b.x); o.h[5] = __float2bfloat16(b.y);
    o.h[6] = __float2bfloat16(b.z); o.h[7] = __float2bfloat16(b.w);
    *(uint4*)(y + i) = o.u;
}

// ---------------------------------------------------------------------------
// Kernel 2: W_eff[n][k] = dequant_int4(qw, wscales) + wtscale * (pu @ pd)
// tile: 64 n x 128 k per block, 256 threads; thread = 4n x 8k
// 16B qweight loads, 16B bf16 stores
// ---------------------------------------------------------------------------
__global__ __launch_bounds__(256) void build_weff(
    const int* __restrict__ qw,        // [N][K/2] two nibbles per int
    const float* __restrict__ wsc,     // [K/64][N]
    const float* __restrict__ pd,      // [R][K]
    const float* __restrict__ pu,      // [N][R]
    const float* __restrict__ wts_p,   // [1]
    __hip_bfloat16* __restrict__ weff) // [N][K]
{
    __shared__ float pd_s[RD][132];  // padded +4 floats: kills 8-float-stride conflicts
    __shared__ float pu_t[RD][68];   // [r][n] transposed, padded
    const int t = threadIdx.x;
    const int kb = blockIdx.x * 128;
    const int nb = blockIdx.y * 64;

    // stage pd tile: 32x128 floats = 1024 float4, coalesced
    for (int f = t; f < (RD * 128) / 4; f += 256) {
        int r = f >> 5;
        int c = (f & 31) << 2;
        *(float4*)&pd_s[r][c] = *(const float4*)(pd + (size_t)r * KD + kb + c);
    }
    // stage pu tile transposed: 64x32 floats = 512 float4
    for (int f = t; f < (64 * RD) / 4; f += 256) {
        int nl = f >> 3;
        int r4 = (f & 7) << 2;
        float4 v = *(const float4*)(pu + (size_t)(nb + nl) * RD + r4);
        pu_t[r4 + 0][nl] = v.x; pu_t[r4 + 1][nl] = v.y;
        pu_t[r4 + 2][nl] = v.z; pu_t[r4 + 3][nl] = v.w;
    }
    __syncthreads();

    const float wts = wts_p[0];
    const int kc = (t & 15) << 3;   // local k base (8 cols)
    const int ng = (t >> 4) << 2;   // local n base (4 rows)

    float acc[4][8];
#pragma unroll
    for (int i = 0; i < 4; ++i)
#pragma unroll
        for (int j = 0; j < 8; ++j) acc[i][j] = 0.f;

    for (int r = 0; r < RD; ++r) {
        float4 pda = *(const float4*)&pd_s[r][kc];
        float4 pdb = *(const float4*)&pd_s[r][kc + 4];
        float4 puv = *(const float4*)&pu_t[r][ng];
        float pus[4] = {puv.x, puv.y, puv.z, puv.w};
        float pdv[8] = {pda.x, pda.y, pda.z, pda.w, pdb.x, pdb.y, pdb.z, pdb.w};
#pragma unroll
        for (int i = 0; i < 4; ++i)
#pragma unroll
            for (int j = 0; j < 8; ++j)
                acc[i][j] += pus[i] * pdv[j];
    }

    const int kg = kb + kc;       // global k base; 8 k's share one group
    const int g = kg >> 6;        // group index (GROUP_SIZE=64)
#pragma unroll
    for (int i = 0; i < 4; ++i) {
        const int n = nb + ng + i;
        const float sc = wsc[(size_t)g * ND + n];
        int4 q = *(const int4*)(qw + (size_t)n * (KD / 2) + (kg >> 1));
        const int qi[4] = {q.x, q.y, q.z, q.w};
        union { __hip_bfloat16 h[8]; uint4 u; } o;
#pragma unroll
        for (int j = 0; j < 4; ++j) {
            const int lo = (qi[j] & 15) - 8;
            const int hi = ((qi[j] >> 4) & 15) - 8;
            o.h[2 * j]     = __float2bfloat16((float)lo * sc + wts * acc[i][2 * j]);
            o.h[2 * j + 1] = __float2bfloat16((float)hi * sc + wts * acc[i][2 * j + 1]);
        }
        *(uint4*)(weff + (size_t)n * KD + kg) = o.u;
    }
}

// ---------------------------------------------------------------------------
// Kernel 3: C[M][N] = A[M][K](bf16) * B[N][K](bf16)^T + bias   (m97 structure
// + LDS chunk XOR-swizzle + XCD-aware block remap)
// 128x128 tile, BK=32, 256 threads = 4 waves (2x2), wave = 64x64 (4x4 MFMA)
// ---------------------------------------------------------------------------
__global__ __launch_bounds__(256) void gemm_bt_bias(
    const __hip_bfloat16* __restrict__ A,  // [M][K]
    const __hip_bfloat16* __restrict__ B,  // [N][K]
    const float* __restrict__ bias,        // [N]
    float* __restrict__ C)                 // [M][N]
{
    __shared__ alignas(16) __hip_bfloat16 As[128 * 32]; // 8 KB, row-major [m][k-chunk swizzled]
    __shared__ alignas(16) __hip_bfloat16 Bs[128 * 32]; // 8 KB

    const int t = threadIdx.x;
    const int lane = t & 63;
    const int wave = t >> 6;
    const int wr = wave >> 1;   // wave row (m)  0..1
    const int wc = wave & 1;    // wave col (n)  0..1

    // XCD-aware remap: grid is 1-D 2048 = 64 m-tiles x 32 n-tiles.
    // xcd = bid&7 owns n-band of 4 tiles (4 MB of B = one XCD L2);
    // all XCDs sweep the same m-tile concurrently -> A-tile HBM-fetched once, L3-hit 8x.
    const int bid = blockIdx.x;
    const int nb = (bid & 7) * 4 + ((bid >> 3) & 3);
    const int mb = bid >> 5;
    const int m0 = mb * 128;
    const int n0 = nb * 128;

    // staging map: pass p covers rows p*64..+63; thread t -> row t/4.
    // chunk XOR-swizzle: LDS slot (t&3) holds global chunk (t&3)^((row>>1)&3)
    const int srow = t >> 2;
    const int scol = ((t & 3) ^ ((t >> 3) & 3)) * 8;
    const __hip_bfloat16* Ag = A + (size_t)(m0 + srow) * KD + scol;
    const __hip_bfloat16* Bg = B + (size_t)(n0 + srow) * KD + scol;
    char* AsB = (char*)As + wave * 1024;  // wave-uniform LDS base, pass 0
    char* BsB = (char*)Bs + wave * 1024;

    const int qm = lane & 15;        // row-within-16 (A: m, B: n)
    // swizzled k-chunk offset: global chunk (lane>>4) lives in LDS slot (lane>>4)^((row>>1)&3);
    // (row>>1)&3 == (qm>>1)&3 for every fragment row (i*16, wave*64 are 0 mod 8)
    const int ko_sw = (((lane >> 4) ^ ((qm >> 1) & 3))) * 8;

    f32x4 acc[4][4];
#pragma unroll
    for (int i = 0; i < 4; ++i)
#pragma unroll
        for (int j = 0; j < 4; ++j) acc[i][j] = (f32x4){0.f, 0.f, 0.f, 0.f};

    for (int kt = 0; kt < KD; kt += 32) {
        // stage A,B tiles: 2 passes each, 16B/lane async
        cp16(Ag + kt, AsB);
        cp16(Ag + kt + 64 * KD, AsB + 4096);
        cp16(Bg + kt, BsB);
        cp16(Bg + kt + 64 * KD, BsB + 4096);
        __syncthreads();

        bf16x8 af[4], bfr[4];
#pragma unroll
        for (int i = 0; i < 4; ++i)
            af[i] = *(const bf16x8*)(As + (wr * 64 + i * 16 + qm) * 32 + ko_sw);
#pragma unroll
        for (int j = 0; j < 4; ++j)
            bfr[j] = *(const bf16x8*)(Bs + (wc * 64 + j * 16 + qm) * 32 + ko_sw);

#pragma unroll
        for (int i = 0; i < 4; ++i)
#pragma unroll
            for (int j = 0; j < 4; ++j)
                acc[i][j] = __builtin_amdgcn_mfma_f32_16x16x32_bf16(
                    af[i], bfr[j], acc[i][j], 0, 0, 0);
        __syncthreads();
    }

    // epilogue: C/D layout col=lane&15, row=(lane>>4)*4+reg
    const int cm0 = (lane >> 4) * 4;
    const int cn = lane & 15;
#pragma unroll
    for (int j = 0; j < 4; ++j) {
        const int n = n0 + wc * 64 + j * 16 + cn;
        const float bv = bias[n];
#pragma unroll
        for (int i = 0; i < 4; ++i) {
            const int mr = m0 + wr * 64 + i * 16 + cm0;
            float* dst = C + (size_t)mr * ND + n;
#pragma unroll
            for (int r = 0; r < 4; ++r)
                dst[(size_t)r * ND] = acc[i][j][r] + bv;
        }
    }
}

// ---------------------------------------------------------------------------
extern "C" void kernel_launch(void* const* d_in, const int* in_sizes, int n_in,
                              void* d_out, int out_size, void* d_ws, size_t ws_size,
                              hipStream_t stream) {
    const float* x    = (const float*)d_in[0];   // [M][K] fp32
    const int* qw     = (const int*)d_in[1];     // [N][K/2]
    const float* wsc  = (const float*)d_in[2];   // [K/64][N]
    const float* pd   = (const float*)d_in[3];   // [R][K]
    const float* pu   = (const float*)d_in[4];   // [N][R]
    const float* wts  = (const float*)d_in[5];   // [1]
    const float* bias = (const float*)d_in[6];   // [N]
    float* out = (float*)d_out;                  // [M][N] fp32

    // workspace: W_eff bf16 (33.5 MB) then x bf16 (67 MB) = 100.7 MB
    __hip_bfloat16* weff = (__hip_bfloat16*)d_ws;
    __hip_bfloat16* xbf  = (__hip_bfloat16*)((char*)d_ws + (size_t)ND * KD * sizeof(__hip_bfloat16));

    cvt_x<<<(MD * (size_t)KD) / (256 * 8), 256, 0, stream>>>(x, xbf);
    build_weff<<<dim3(KD / 128, ND / 64), 256, 0, stream>>>(qw, wsc, pd, pu, wts, weff);
    gemm_bt_bias<<<2048, 256, 0, stream>>>(xbf, weff, bias, out);
}

// Round 3
// 534.689 us; speedup vs baseline: 1.0566x; 1.0566x over previous
//
#include <hip/hip_runtime.h>
#include <hip/hip_bf16.h>
#include <stdint.h>

// Problem dims (fixed for this problem instance)
#define MD 8192
#define ND 4096
#define KD 4096
#define RD 32

typedef __bf16 bf16x8 __attribute__((ext_vector_type(8)));
typedef float f32x4 __attribute__((ext_vector_type(4)));

// async 16B global->LDS (wave-uniform LDS base + lane*16 scatter)
__device__ __forceinline__ void cp16(const void* g, void* l) {
    __builtin_amdgcn_global_load_lds(
        (const __attribute__((address_space(1))) void*)g,
        (__attribute__((address_space(3))) void*)l, 16, 0, 0);
}

// ---------------------------------------------------------------------------
// Kernel 1: x fp32 -> bf16  (8 elems/thread, 16B stores)
// ---------------------------------------------------------------------------
__global__ __launch_bounds__(256) void cvt_x(const float* __restrict__ x,
                                             __hip_bfloat16* __restrict__ y) {
    size_t i = ((size_t)blockIdx.x * 256 + threadIdx.x) * 8;
    float4 a = *(const float4*)(x + i);
    float4 b = *(const float4*)(x + i + 4);
    union { __hip_bfloat16 h[8]; uint4 u; } o;
    o.h[0] = __float2bfloat16(a.x); o.h[1] = __float2bfloat16(a.y);
    o.h[2] = __float2bfloat16(a.z); o.h[3] = __float2bfloat16(a.w);
    o.h[4] = __float2bfloat16(b.x); o.h[5] = __float2bfloat16(b.y);
    o.h[6] = __float2bfloat16(b.z); o.h[7] = __float2bfloat16(b.w);
    *(uint4*)(y + i) = o.u;
}

// ---------------------------------------------------------------------------
// Kernel 2: W_eff[n][k] = dequant_int4(qw, wscales) + wtscale * (pu @ pd)
// tile: 64 n x 128 k per block, 256 threads; thread = 4n x 8k
// ---------------------------------------------------------------------------
__global__ __launch_bounds__(256) void build_weff(
    const int* __restrict__ qw,        // [N][K/2] two nibbles per int
    const float* __restrict__ wsc,     // [K/64][N]
    const float* __restrict__ pd,      // [R][K]
    const float* __restrict__ pu,      // [N][R]
    const float* __restrict__ wts_p,   // [1]
    __hip_bfloat16* __restrict__ weff) // [N][K]
{
    __shared__ float pd_s[RD][132];
    __shared__ float pu_t[RD][68];
    const int t = threadIdx.x;
    const int kb = blockIdx.x * 128;
    const int nb = blockIdx.y * 64;

    for (int f = t; f < (RD * 128) / 4; f += 256) {
        int r = f >> 5;
        int c = (f & 31) << 2;
        *(float4*)&pd_s[r][c] = *(const float4*)(pd + (size_t)r * KD + kb + c);
    }
    for (int f = t; f < (64 * RD) / 4; f += 256) {
        int nl = f >> 3;
        int r4 = (f & 7) << 2;
        float4 v = *(const float4*)(pu + (size_t)(nb + nl) * RD + r4);
        pu_t[r4 + 0][nl] = v.x; pu_t[r4 + 1][nl] = v.y;
        pu_t[r4 + 2][nl] = v.z; pu_t[r4 + 3][nl] = v.w;
    }
    __syncthreads();

    const float wts = wts_p[0];
    const int kc = (t & 15) << 3;   // local k base (8 cols)
    const int ng = (t >> 4) << 2;   // local n base (4 rows)

    float acc[4][8];
#pragma unroll
    for (int i = 0; i < 4; ++i)
#pragma unroll
        for (int j = 0; j < 8; ++j) acc[i][j] = 0.f;

    for (int r = 0; r < RD; ++r) {
        float4 pda = *(const float4*)&pd_s[r][kc];
        float4 pdb = *(const float4*)&pd_s[r][kc + 4];
        float4 puv = *(const float4*)&pu_t[r][ng];
        float pus[4] = {puv.x, puv.y, puv.z, puv.w};
        float pdv[8] = {pda.x, pda.y, pda.z, pda.w, pdb.x, pdb.y, pdb.z, pdb.w};
#pragma unroll
        for (int i = 0; i < 4; ++i)
#pragma unroll
            for (int j = 0; j < 8; ++j)
                acc[i][j] += pus[i] * pdv[j];
    }

    const int kg = kb + kc;
    const int g = kg >> 6;
#pragma unroll
    for (int i = 0; i < 4; ++i) {
        const int n = nb + ng + i;
        const float sc = wsc[(size_t)g * ND + n];
        int4 q = *(const int4*)(qw + (size_t)n * (KD / 2) + (kg >> 1));
        const int qi[4] = {q.x, q.y, q.z, q.w};
        union { __hip_bfloat16 h[8]; uint4 u; } o;
#pragma unroll
        for (int j = 0; j < 4; ++j) {
            const int lo = (qi[j] & 15) - 8;
            const int hi = ((qi[j] >> 4) & 15) - 8;
            o.h[2 * j]     = __float2bfloat16((float)lo * sc + wts * acc[i][2 * j]);
            o.h[2 * j + 1] = __float2bfloat16((float)hi * sc + wts * acc[i][2 * j + 1]);
        }
        *(uint4*)(weff + (size_t)n * KD + kg) = o.u;
    }
}

// ---------------------------------------------------------------------------
// Kernel 3: C[M][N] = A[M][K](bf16) * B[N][K](bf16)^T + bias
// BK=64: 32 MFMA per barrier pair (vs 16 at BK=32) to amortize the vmcnt
// drain. 128x128 tile, 256 threads = 4 waves (2x2), wave = 64x64 (4x4 MFMA,
// 2 k-halves). LDS 32 KB. Chunk XOR-swizzle (slot = chunk ^ (row&7)) keeps
// reads conflict-free; XCD-aware block remap.
// ---------------------------------------------------------------------------
__global__ __launch_bounds__(256) void gemm_bt_bias(
    const __hip_bfloat16* __restrict__ A,  // [M][K]
    const __hip_bfloat16* __restrict__ B,  // [N][K]
    const float* __restrict__ bias,        // [N]
    float* __restrict__ C)                 // [M][N]
{
    __shared__ alignas(16) __hip_bfloat16 As[128 * 64]; // 16 KB, [m][k-chunk swizzled]
    __shared__ alignas(16) __hip_bfloat16 Bs[128 * 64]; // 16 KB

    const int t = threadIdx.x;
    const int lane = t & 63;
    const int wave = t >> 6;
    const int wr = wave >> 1;   // wave row (m)  0..1
    const int wc = wave & 1;    // wave col (n)  0..1

    // XCD-aware remap: 2048 blocks = 64 m-tiles x 32 n-tiles.
    const int bid = blockIdx.x;
    const int nb = (bid & 7) * 4 + ((bid >> 3) & 3);
    const int mb = bid >> 5;
    const int m0 = mb * 128;
    const int n0 = nb * 128;

    // staging: pass p covers rows p*32..+31; thread t -> row t>>3, LDS slot t&7.
    // global chunk fetched for LDS slot s of row r is s ^ (r&7).
    const int srow = t >> 3;
    const int gchunk = (t & 7) ^ ((t >> 3) & 7);
    const __hip_bfloat16* Ag = A + (size_t)(m0 + srow) * KD + gchunk * 8;
    const __hip_bfloat16* Bg = B + (size_t)(n0 + srow) * KD + gchunk * 8;
    char* AsB = (char*)As + wave * 1024;  // wave-uniform LDS base, pass 0
    char* BsB = (char*)Bs + wave * 1024;

    const int qm = lane & 15;       // row-within-16 (A: m, B: n)
    const int c = lane >> 4;        // k-chunk 0..3 within a 32-k half
    // LDS slot for k-half h, fragment row ..+qm: (h*4 + c) ^ (qm&7)
    const int sl0 = ((c) ^ (qm & 7)) * 8;
    const int sl1 = ((4 + c) ^ (qm & 7)) * 8;

    f32x4 acc[4][4];
#pragma unroll
    for (int i = 0; i < 4; ++i)
#pragma unroll
        for (int j = 0; j < 4; ++j) acc[i][j] = (f32x4){0.f, 0.f, 0.f, 0.f};

    for (int kt = 0; kt < KD; kt += 64) {
        // stage A,B 128x64 tiles: 4 passes each, 16B/lane async
#pragma unroll
        for (int p = 0; p < 4; ++p) {
            cp16(Ag + kt + (size_t)p * 32 * KD, AsB + p * 4096);
            cp16(Bg + kt + (size_t)p * 32 * KD, BsB + p * 4096);
        }
        __syncthreads();

        bf16x8 af[4][2], bfr[4][2];
#pragma unroll
        for (int i = 0; i < 4; ++i) {
            const int row = (wr * 64 + i * 16 + qm) * 64;
            af[i][0] = *(const bf16x8*)(As + row + sl0);
            af[i][1] = *(const bf16x8*)(As + row + sl1);
        }
#pragma unroll
        for (int j = 0; j < 4; ++j) {
            const int row = (wc * 64 + j * 16 + qm) * 64;
            bfr[j][0] = *(const bf16x8*)(Bs + row + sl0);
            bfr[j][1] = *(const bf16x8*)(Bs + row + sl1);
        }

#pragma unroll
        for (int i = 0; i < 4; ++i)
#pragma unroll
            for (int j = 0; j < 4; ++j)
                acc[i][j] = __builtin_amdgcn_mfma_f32_16x16x32_bf16(
                    af[i][0], bfr[j][0], acc[i][j], 0, 0, 0);
#pragma unroll
        for (int i = 0; i < 4; ++i)
#pragma unroll
            for (int j = 0; j < 4; ++j)
                acc[i][j] = __builtin_amdgcn_mfma_f32_16x16x32_bf16(
                    af[i][1], bfr[j][1], acc[i][j], 0, 0, 0);
        __syncthreads();
    }

    // epilogue: C/D layout col=lane&15, row=(lane>>4)*4+reg
    const int cm0 = (lane >> 4) * 4;
    const int cn = lane & 15;
#pragma unroll
    for (int j = 0; j < 4; ++j) {
        const int n = n0 + wc * 64 + j * 16 + cn;
        const float bv = bias[n];
#pragma unroll
        for (int i = 0; i < 4; ++i) {
            const int mr = m0 + wr * 64 + i * 16 + cm0;
            float* dst = C + (size_t)mr * ND + n;
#pragma unroll
            for (int r = 0; r < 4; ++r)
                dst[(size_t)r * ND] = acc[i][j][r] + bv;
        }
    }
}

// ---------------------------------------------------------------------------
extern "C" void kernel_launch(void* const* d_in, const int* in_sizes, int n_in,
                              void* d_out, int out_size, void* d_ws, size_t ws_size,
                              hipStream_t stream) {
    const float* x    = (const float*)d_in[0];   // [M][K] fp32
    const int* qw     = (const int*)d_in[1];     // [N][K/2]
    const float* wsc  = (const float*)d_in[2];   // [K/64][N]
    const float* pd   = (const float*)d_in[3];   // [R][K]
    const float* pu   = (const float*)d_in[4];   // [N][R]
    const float* wts  = (const float*)d_in[5];   // [1]
    const float* bias = (const float*)d_in[6];   // [N]
    float* out = (float*)d_out;                  // [M][N] fp32

    __hip_bfloat16* weff = (__hip_bfloat16*)d_ws;
    __hip_bfloat16* xbf  = (__hip_bfloat16*)((char*)d_ws + (size_t)ND * KD * sizeof(__hip_bfloat16));

    cvt_x<<<(MD * (size_t)KD) / (256 * 8), 256, 0, stream>>>(x, xbf);
    build_weff<<<dim3(KD / 128, ND / 64), 256, 0, stream>>>(qw, wsc, pd, pu, wts, weff);
    gemm_bt_bias<<<2048, 256, 0, stream>>>(xbf, weff, bias, out);
}